// Round 12
// baseline (87.522 us; speedup 1.0000x reference)
//
#include <hip/hip_runtime.h>
#include <stdint.h>
#include <stddef.h>

#define S_LEN 2048
#define DMODEL 1024
#define NHEAD 16
#define HDIM 64
#define WINSZ 256
#define MROWS 4096
#define NQKV 3072

typedef __bf16 bf16x8 __attribute__((ext_vector_type(8)));
typedef float f32x4 __attribute__((ext_vector_type(4)));
typedef unsigned short us4 __attribute__((ext_vector_type(4)));
typedef unsigned short us8 __attribute__((ext_vector_type(8)));

#define MFMA16(a, b, c) __builtin_amdgcn_mfma_f32_16x16x32_bf16((a), (b), (c), 0, 0, 0)

__device__ __forceinline__ unsigned short f2b(float f) {
  union { float f; unsigned u; } v; v.f = f;
  unsigned u = v.u;
  unsigned r = (u + 0x7FFFu + ((u >> 16) & 1u)) >> 16;
  return (unsigned short)r;
}
__device__ __forceinline__ void storev(float* p, float v) { *p = v; }
__device__ __forceinline__ void storev(unsigned short* p, float v) { *p = f2b(v); }

__device__ __forceinline__ void gload_lds16(const unsigned short* g, unsigned short* l) {
  __builtin_amdgcn_global_load_lds(
      (const __attribute__((address_space(1))) unsigned int*)g,
      (__attribute__((address_space(3))) unsigned int*)l, 16, 0, 0);
}

// ---------------- fused prep kernel ----------------

__global__ void prep_kernel(const float* __restrict__ x,
                            const float* __restrict__ Wq, const float* __restrict__ Wk,
                            const float* __restrict__ Wv, const float* __restrict__ Wo,
                            const float* __restrict__ bq, const float* __restrict__ bk,
                            const float* __restrict__ bv,
                            unsigned short* __restrict__ xb, unsigned short* __restrict__ WqkvT,
                            unsigned short* __restrict__ WoT, float* __restrict__ bqkv) {
  __shared__ float tile[32][33];
  const int bid = blockIdx.x;
  const int tid = threadIdx.x;
  if (bid < 4096) {
    int i = (bid * 256 + tid) * 4;
    float4 v = *reinterpret_cast<const float4*>(x + i);
    us4 o;
    o[0] = f2b(v.x); o[1] = f2b(v.y); o[2] = f2b(v.z); o[3] = f2b(v.w);
    *reinterpret_cast<us4*>(xb + i) = o;
  } else if (bid < 8192) {
    int z = (bid - 4096) >> 10;
    int rem = (bid - 4096) & 1023;
    int bx = rem & 31, by = rem >> 5;
    const float* W = (z == 0) ? Wq : (z == 1) ? Wk : (z == 2) ? Wv : Wo;
    unsigned short* Wt = (z == 3) ? WoT : WqkvT + (size_t)z * DMODEL * DMODEL;
    int n0 = bx * 32, k0 = by * 32;
    int tx = tid & 31, ty = tid >> 5;
#pragma unroll
    for (int i = 0; i < 32; i += 8)
      tile[ty + i][tx] = W[(size_t)(k0 + ty + i) * DMODEL + n0 + tx];
    __syncthreads();
#pragma unroll
    for (int i = 0; i < 32; i += 8)
      Wt[(size_t)(n0 + ty + i) * DMODEL + k0 + tx] = f2b(tile[tx][ty + i]);
  } else {
    int i = (bid - 8192) * 256 + tid;
    if (i < DMODEL) {
      bqkv[i] = bq[i];
      bqkv[DMODEL + i] = bk[i];
      bqkv[2 * DMODEL + i] = bv[i];
    }
  }
}

// ---------------- 2-phase 128x192 GEMM (QKV projection) ----------------
// Round-9 config + 2-bit swizzle: col bits {4,5}(elems) ^= row bits {2,1}.
// One-bit swizzle left each b128 wave-read on 16 of 32 banks (rows are
// 128B = bank-aligned); second bit spreads each lg group over all 8
// 4-bank groups -> 8 touches/bank = conflict-free minimum.

__global__ __launch_bounds__(512, 4) void gemmqkv_kernel(
    const unsigned short* __restrict__ A, const unsigned short* __restrict__ Bt,
    const float* __restrict__ bias, unsigned short* __restrict__ C, int N, int K) {
  __shared__ unsigned short As[2 * 128 * 64];
  __shared__ unsigned short Bs[2 * 192 * 64];
  const int tid = threadIdx.x;
  const int cpx = gridDim.x >> 3;
  const int nid = (blockIdx.x & 7) * cpx + (blockIdx.x >> 3);
  const int nbx = N / 192;
  const int by = nid / nbx, bx = nid - by * nbx;
  const int m0 = by * 128, n0 = bx * 192;
  const int wid = tid >> 6, l = tid & 63;
  const int wm = wid >> 2, wn = wid & 3;
  const int lr = l & 15, lg = l >> 4;
  const int srow = tid >> 3;                       // 0..63
  const int scol = (tid & 7) * 8;
  // pre-swizzle: row bit2 = tid bit5, row bit1 = tid bit4
  const int scol_g = scol ^ (((tid >> 5) & 1) << 4) ^ (((tid >> 4) & 1) << 5);
  const int NT = K >> 6;

  f32x4 acc[4][3];
#pragma unroll
  for (int i = 0; i < 4; i++)
#pragma unroll
    for (int j = 0; j < 3; j++) acc[i][j] = (f32x4){0.f, 0.f, 0.f, 0.f};

  auto stage = [&](int buf, int kt) {
#pragma unroll
    for (int r = 0; r < 2; r++)
      gload_lds16(A + (size_t)(m0 + r * 64 + srow) * K + kt * 64 + scol_g,
                  &As[((buf * 2 + r) * 64 + srow) * 64 + scol]);
#pragma unroll
    for (int c = 0; c < 3; c++)
      gload_lds16(Bt + (size_t)(n0 + c * 64 + srow) * K + kt * 64 + scol_g,
                  &Bs[((buf * 3 + c) * 64 + srow) * 64 + scol]);
  };

  stage(0, 0);
  asm volatile("s_waitcnt vmcnt(0)" ::: "memory");
  __builtin_amdgcn_s_barrier();

  // read-side swizzle: same 2-bit involution (row bits from lr)
  const int colr = (lg * 8) ^ (((lr >> 2) & 1) << 4) ^ (((lr >> 1) & 1) << 5);
  const int aB = (wm * 64 + lr) * 64 + colr;
  int bOff[3];
#pragma unroll
  for (int j = 0; j < 3; j++)
    bOff[j] = (wn * 48 + j * 16 + lr) * 64 + colr;

  int cur = 0;
#pragma unroll 1
  for (int t = 0; t < NT; t++) {
    if (t + 1 < NT) stage(cur ^ 1, t + 1);  // issue first; overlaps with compute
    bf16x8 a[4][2], b[3][2];
#pragma unroll
    for (int i = 0; i < 4; i++)
#pragma unroll
      for (int kk = 0; kk < 2; kk++)
        a[i][kk] = *reinterpret_cast<const bf16x8*>(&As[cur * 8192 + i * 1024 + ((kk * 32) ^ (aB & 96)) + (aB & ~96)]);
#pragma unroll
    for (int j = 0; j < 3; j++)
#pragma unroll
      for (int kk = 0; kk < 2; kk++)
        b[j][kk] = *reinterpret_cast<const bf16x8*>(&Bs[cur * 12288 + ((kk * 32) ^ (bOff[j] & 96)) + (bOff[j] & ~96)]);
    __builtin_amdgcn_s_setprio(1);
#pragma unroll
    for (int i = 0; i < 4; i++)
#pragma unroll
      for (int j = 0; j < 3; j++)
#pragma unroll
        for (int kk = 0; kk < 2; kk++)
          acc[i][j] = MFMA16(a[i][kk], b[j][kk], acc[i][j]);
    __builtin_amdgcn_s_setprio(0);
    asm volatile("s_waitcnt vmcnt(0)" ::: "memory");
    __builtin_amdgcn_s_barrier();
    cur ^= 1;
  }

#pragma unroll
  for (int i = 0; i < 4; i++) {
    int row = m0 + wm * 64 + i * 16 + lg * 4;
#pragma unroll
    for (int j = 0; j < 3; j++) {
      int col = n0 + wn * 48 + j * 16 + lr;
      float bsv = bias[col];
#pragma unroll
      for (int r = 0; r < 4; r++)
        C[(size_t)(row + r) * N + col] = f2b(acc[i][j][r] + bsv);
    }
  }
}

// ---------------- 2-phase 128x64 GEMM (output projection) ----------------
// Same 2-bit swizzle.

template <typename OutT>
__global__ __launch_bounds__(256, 3) void gemm2p_kernel(
    const unsigned short* __restrict__ A, const unsigned short* __restrict__ Bt,
    const float* __restrict__ bias, OutT* __restrict__ C, int N, int K) {
  __shared__ unsigned short As[2 * 128 * 64];
  __shared__ unsigned short Bs[2 * 64 * 64];
  const int tid = threadIdx.x;
  const int cpx = gridDim.x >> 3;
  const int nid = (blockIdx.x & 7) * cpx + (blockIdx.x >> 3);
  const int nbx = N >> 6;
  const int by = nid / nbx, bx = nid - by * nbx;
  const int m0 = by * 128, n0 = bx * 64;
  const int w = tid >> 6, l = tid & 63;
  const int wm = (w >> 1) * 64, wn = (w & 1) * 32;
  const int lr = l & 15, lg = l >> 4;
  const int srow = tid >> 3;
  const int scol = (tid & 7) * 8;
  const int scol_g = scol ^ (((tid >> 5) & 1) << 4) ^ (((tid >> 4) & 1) << 5);
  const int NT = K >> 6;

  f32x4 acc[4][2];
#pragma unroll
  for (int i = 0; i < 4; i++)
#pragma unroll
    for (int j = 0; j < 2; j++) acc[i][j] = (f32x4){0.f, 0.f, 0.f, 0.f};

  auto stage = [&](int buf, int kt) {
#pragma unroll
    for (int r = 0; r < 4; r++)
      gload_lds16(A + (size_t)(m0 + r * 32 + srow) * K + kt * 64 + scol_g,
                  &As[(buf * 128 + r * 32 + srow) * 64 + scol]);
#pragma unroll
    for (int r = 0; r < 2; r++)
      gload_lds16(Bt + (size_t)(n0 + r * 32 + srow) * K + kt * 64 + scol_g,
                  &Bs[(buf * 64 + r * 32 + srow) * 64 + scol]);
  };

  stage(0, 0);
  asm volatile("s_waitcnt vmcnt(0)" ::: "memory");
  __builtin_amdgcn_s_barrier();

  const int colr = (lg * 8) ^ (((lr >> 2) & 1) << 4) ^ (((lr >> 1) & 1) << 5);
  const int aB = (wm + lr) * 64 + colr;
  const int bB = (wn + lr) * 64 + colr;

  int cur = 0;
#pragma unroll 1
  for (int t = 0; t < NT; t++) {
    if (t + 1 < NT) stage(cur ^ 1, t + 1);
    bf16x8 a[4][2], b[2][2];
#pragma unroll
    for (int i = 0; i < 4; i++)
#pragma unroll
      for (int kk = 0; kk < 2; kk++)
        a[i][kk] = *reinterpret_cast<const bf16x8*>(&As[cur * 8192 + i * 1024 + ((kk * 32) ^ (aB & 96)) + (aB & ~96)]);
#pragma unroll
    for (int j = 0; j < 2; j++)
#pragma unroll
      for (int kk = 0; kk < 2; kk++)
        b[j][kk] = *reinterpret_cast<const bf16x8*>(&Bs[cur * 4096 + j * 1024 + ((kk * 32) ^ (bB & 96)) + (bB & ~96)]);
    __builtin_amdgcn_s_setprio(1);
#pragma unroll
    for (int i = 0; i < 4; i++)
#pragma unroll
      for (int j = 0; j < 2; j++)
#pragma unroll
        for (int kk = 0; kk < 2; kk++)
          acc[i][j] = MFMA16(a[i][kk], b[j][kk], acc[i][j]);
    __builtin_amdgcn_s_setprio(0);
    asm volatile("s_waitcnt vmcnt(0)" ::: "memory");
    __builtin_amdgcn_s_barrier();
    cur ^= 1;
  }

#pragma unroll
  for (int i = 0; i < 4; i++) {
    int row = m0 + wm + i * 16 + lg * 4;
#pragma unroll
    for (int j = 0; j < 2; j++) {
      int col = n0 + wn + j * 16 + lr;
      float bsv = bias[col];
#pragma unroll
      for (int r = 0; r < 4; r++)
        storev(&C[(size_t)(row + r) * N + col], acc[i][j][r] + bsv);
    }
  }
}

// ---------------- windowed flash attention (128 q-rows/block) ----------------

__global__ __launch_bounds__(512) void attn_kernel(const unsigned short* __restrict__ qkv,
                                                   unsigned short* __restrict__ attnb) {
  __shared__ unsigned short Ks[64 * 72];
  __shared__ unsigned short Vt[64 * 72];
  __shared__ unsigned short Ps[8][16 * 72];

  const int tid = threadIdx.x;
  const int i0 = blockIdx.x * 128;
  const int h = blockIdx.y;
  const int b = blockIdx.z;
  const int w = tid >> 6, l = tid & 63;
  const int lr = l & 15, lg = l >> 4;
  const size_t rowb = (size_t)b * S_LEN;

  const unsigned short* qptr = qkv + (rowb + i0 + w * 16 + lr) * NQKV + h * HDIM;
  bf16x8 qa[2];
  qa[0] = *reinterpret_cast<const bf16x8*>(qptr + lg * 8);
  qa[1] = *reinterpret_cast<const bf16x8*>(qptr + 32 + lg * 8);

  f32x4 accO[4];
#pragma unroll
  for (int f = 0; f < 4; f++) accO[f] = (f32x4){0.f, 0.f, 0.f, 0.f};
  float Mv[4], Lv[4];
#pragma unroll
  for (int r = 0; r < 4; r++) { Mv[r] = -1e30f; Lv[r] = 0.f; }

  const int wimin = i0 + w * 16;
  const int wimax = wimin + 15;

  for (int c = 0; c < 6; c++) {
    int j0c = i0 - WINSZ + c * 64;
    if (j0c + 63 < 0) continue;  // block-uniform
    __syncthreads();
    {
      int d8 = (tid & 7) * 8;
      int jl = tid >> 3;  // 0..63
      int jg = j0c + jl;
      us8 kv = (us8){0, 0, 0, 0, 0, 0, 0, 0}, vv = (us8){0, 0, 0, 0, 0, 0, 0, 0};
      if (jg >= 0) {
        const unsigned short* kp = qkv + (rowb + jg) * NQKV + DMODEL + h * HDIM + d8;
        kv = *reinterpret_cast<const us8*>(kp);
        vv = *reinterpret_cast<const us8*>(kp + DMODEL);
      }
      *reinterpret_cast<us8*>(&Ks[jl * 72 + d8]) = kv;
      int jsw = jl ^ ((tid & 3) << 3);
#pragma unroll
      for (int e = 0; e < 8; e++) Vt[(d8 + e) * 72 + jsw] = vv[e];
    }
    __syncthreads();

    if (j0c > wimax || j0c + 63 < wimin - WINSZ) continue;  // wave-uniform

    f32x4 sa[4];
#pragma unroll
    for (int f = 0; f < 4; f++) sa[f] = (f32x4){0.f, 0.f, 0.f, 0.f};
#pragma unroll
    for (int f = 0; f < 4; f++) {
      bf16x8 k0v = *reinterpret_cast<const bf16x8*>(&Ks[(f * 16 + lr) * 72 + lg * 8]);
      bf16x8 k1v = *reinterpret_cast<const bf16x8*>(&Ks[(f * 16 + lr) * 72 + 32 + lg * 8]);
      sa[f] = MFMA16(qa[0], k0v, sa[f]);
      sa[f] = MFMA16(qa[1], k1v, sa[f]);
    }
#pragma unroll
    for (int f = 0; f < 4; f++) {
      int jg = j0c + f * 16 + lr;
#pragma unroll
      for (int r = 0; r < 4; r++) {
        int irow = i0 + w * 16 + lg * 4 + r;
        float s = sa[f][r] * 0.125f;
        bool ok = (jg >= 0) && (jg <= irow) && (jg >= irow - WINSZ);
        sa[f][r] = ok ? s : -1e30f;
      }
    }
    float pm[4];
#pragma unroll
    for (int r = 0; r < 4; r++) {
      float m = fmaxf(fmaxf(sa[0][r], sa[1][r]), fmaxf(sa[2][r], sa[3][r]));
#pragma unroll
      for (int off = 1; off < 16; off <<= 1) m = fmaxf(m, __shfl_xor(m, off));
      pm[r] = m;
    }
#pragma unroll
    for (int r = 0; r < 4; r++) {
      float Mn = fmaxf(Mv[r], pm[r]);
      float sc = __expf(Mv[r] - Mn);
      Mv[r] = Mn;
      Lv[r] *= sc;
#pragma unroll
      for (int f = 0; f < 4; f++) accO[f][r] *= sc;
    }
    float rs[4] = {0.f, 0.f, 0.f, 0.f};
#pragma unroll
    for (int f = 0; f < 4; f++) {
#pragma unroll
      for (int r = 0; r < 4; r++) {
        float p = __expf(sa[f][r] - Mv[r]);
        rs[r] += p;
        Ps[w][(lg * 4 + r) * 72 + f * 16 + lr] = f2b(p);
      }
    }
#pragma unroll
    for (int r = 0; r < 4; r++) {
      float s = rs[r];
#pragma unroll
      for (int off = 1; off < 16; off <<= 1) s += __shfl_xor(s, off);
      Lv[r] += s;
    }
    bf16x8 pa0 = *reinterpret_cast<const bf16x8*>(&Ps[w][lr * 72 + lg * 8]);
    bf16x8 pa1 = *reinterpret_cast<const bf16x8*>(&Ps[w][lr * 72 + 32 + lg * 8]);
#pragma unroll
    for (int f = 0; f < 4; f++) {
      int vsw = ((f * 2 + (lr >> 3)) & 3) << 3;
      bf16x8 v0 = *reinterpret_cast<const bf16x8*>(&Vt[(f * 16 + lr) * 72 + ((lg * 8) ^ vsw)]);
      bf16x8 v1 = *reinterpret_cast<const bf16x8*>(&Vt[(f * 16 + lr) * 72 + 32 + ((lg * 8) ^ vsw)]);
      accO[f] = MFMA16(pa0, v0, accO[f]);
      accO[f] = MFMA16(pa1, v1, accO[f]);
    }
  }

#pragma unroll
  for (int f = 0; f < 4; f++) {
#pragma unroll
    for (int r = 0; r < 4; r++) {
      float o = accO[f][r] / Lv[r];
      int row = i0 + w * 16 + lg * 4 + r;
      attnb[(rowb + row) * DMODEL + h * HDIM + f * 16 + lr] = f2b(o);
    }
  }
}

// ---------------- launch ----------------

extern "C" void kernel_launch(void* const* d_in, const int* in_sizes, int n_in,
                              void* d_out, int out_size, void* d_ws, size_t ws_size,
                              hipStream_t stream) {
  const float* x = (const float*)d_in[0];
  const float* Wq = (const float*)d_in[1];
  const float* bq = (const float*)d_in[2];
  const float* Wk = (const float*)d_in[3];
  const float* bk = (const float*)d_in[4];
  const float* Wv = (const float*)d_in[5];
  const float* bv = (const float*)d_in[6];
  const float* Wo = (const float*)d_in[7];
  const float* bo = (const float*)d_in[8];
  float* out = (float*)d_out;

  unsigned short* xb = (unsigned short*)d_ws;                       // 4096*1024
  unsigned short* WqkvT = xb + (size_t)MROWS * DMODEL;              // 3*1024*1024
  unsigned short* WoT = WqkvT + (size_t)3 * DMODEL * DMODEL;        // 1024*1024
  unsigned short* QKV = WoT + (size_t)DMODEL * DMODEL;              // 4096*3072
  unsigned short* attnb = QKV + (size_t)MROWS * NQKV;               // 4096*1024
  float* bqkv = (float*)(attnb + (size_t)MROWS * DMODEL);           // 3072 f32

  prep_kernel<<<8196, 256, 0, stream>>>(x, Wq, Wk, Wv, Wo, bq, bk, bv,
                                        xb, WqkvT, WoT, bqkv);

  gemmqkv_kernel<<<(NQKV / 192) * (MROWS / 128), 512, 0, stream>>>(
      xb, WqkvT, bqkv, QKV, NQKV, DMODEL);

  attn_kernel<<<dim3(S_LEN / 128, NHEAD, 2), 512, 0, stream>>>(QKV, attnb);

  gemm2p_kernel<float><<<(DMODEL / 64) * (MROWS / 128), 256, 0, stream>>>(
      attnb, WoT, bo, out, DMODEL, DMODEL);
}

// Round 13
// 82.643 us; speedup vs baseline: 1.0590x; 1.0590x over previous
//
#include <hip/hip_runtime.h>
#include <stdint.h>
#include <stddef.h>

#define S_LEN 2048
#define DMODEL 1024
#define NHEAD 16
#define HDIM 64
#define WINSZ 256
#define MROWS 4096
#define NQKV 3072

typedef __bf16 bf16x8 __attribute__((ext_vector_type(8)));
typedef float f32x4 __attribute__((ext_vector_type(4)));
typedef unsigned short us4 __attribute__((ext_vector_type(4)));
typedef unsigned short us8 __attribute__((ext_vector_type(8)));

#define MFMA16(a, b, c) __builtin_amdgcn_mfma_f32_16x16x32_bf16((a), (b), (c), 0, 0, 0)

__device__ __forceinline__ unsigned short f2b(float f) {
  union { float f; unsigned u; } v; v.f = f;
  unsigned u = v.u;
  unsigned r = (u + 0x7FFFu + ((u >> 16) & 1u)) >> 16;
  return (unsigned short)r;
}
__device__ __forceinline__ void storev(float* p, float v) { *p = v; }
__device__ __forceinline__ void storev(unsigned short* p, float v) { *p = f2b(v); }

__device__ __forceinline__ void gload_lds16(const unsigned short* g, unsigned short* l) {
  __builtin_amdgcn_global_load_lds(
      (const __attribute__((address_space(1))) unsigned int*)g,
      (__attribute__((address_space(3))) unsigned int*)l, 16, 0, 0);
}

// ---------------- fused prep kernel ----------------

__global__ void prep_kernel(const float* __restrict__ x,
                            const float* __restrict__ Wq, const float* __restrict__ Wk,
                            const float* __restrict__ Wv, const float* __restrict__ Wo,
                            const float* __restrict__ bq, const float* __restrict__ bk,
                            const float* __restrict__ bv,
                            unsigned short* __restrict__ xb, unsigned short* __restrict__ WqkvT,
                            unsigned short* __restrict__ WoT, float* __restrict__ bqkv) {
  __shared__ float tile[32][33];
  const int bid = blockIdx.x;
  const int tid = threadIdx.x;
  if (bid < 4096) {
    int i = (bid * 256 + tid) * 4;
    float4 v = *reinterpret_cast<const float4*>(x + i);
    us4 o;
    o[0] = f2b(v.x); o[1] = f2b(v.y); o[2] = f2b(v.z); o[3] = f2b(v.w);
    *reinterpret_cast<us4*>(xb + i) = o;
  } else if (bid < 8192) {
    int z = (bid - 4096) >> 10;
    int rem = (bid - 4096) & 1023;
    int bx = rem & 31, by = rem >> 5;
    const float* W = (z == 0) ? Wq : (z == 1) ? Wk : (z == 2) ? Wv : Wo;
    unsigned short* Wt = (z == 3) ? WoT : WqkvT + (size_t)z * DMODEL * DMODEL;
    int n0 = bx * 32, k0 = by * 32;
    int tx = tid & 31, ty = tid >> 5;
#pragma unroll
    for (int i = 0; i < 32; i += 8)
      tile[ty + i][tx] = W[(size_t)(k0 + ty + i) * DMODEL + n0 + tx];
    __syncthreads();
#pragma unroll
    for (int i = 0; i < 32; i += 8)
      Wt[(size_t)(n0 + ty + i) * DMODEL + k0 + tx] = f2b(tile[tx][ty + i]);
  } else {
    int i = (bid - 8192) * 256 + tid;
    if (i < DMODEL) {
      bqkv[i] = bq[i];
      bqkv[DMODEL + i] = bk[i];
      bqkv[2 * DMODEL + i] = bv[i];
    }
  }
}

// ---------------- 2-phase 128x192 GEMM (QKV projection) ----------------
// Round-9/11 proven config: 512 thr = 8 waves (2M x 4N), wave tile 64x48, BK=64.
// LDS 80KB dbuf -> 2 blocks/CU; grid 512; 1-bit st_16x32 swizzle; no setprio
// (lockstep barrier-synced waves = m190 null regime for T5).

__global__ __launch_bounds__(512, 4) void gemmqkv_kernel(
    const unsigned short* __restrict__ A, const unsigned short* __restrict__ Bt,
    const float* __restrict__ bias, unsigned short* __restrict__ C, int N, int K) {
  __shared__ unsigned short As[2 * 128 * 64];
  __shared__ unsigned short Bs[2 * 192 * 64];
  const int tid = threadIdx.x;
  const int cpx = gridDim.x >> 3;
  const int nid = (blockIdx.x & 7) * cpx + (blockIdx.x >> 3);
  const int nbx = N / 192;
  const int by = nid / nbx, bx = nid - by * nbx;
  const int m0 = by * 128, n0 = bx * 192;
  const int wid = tid >> 6, l = tid & 63;
  const int wm = wid >> 2, wn = wid & 3;
  const int lr = l & 15, lg = l >> 4;
  const int srow = tid >> 3;                       // 0..63
  const int scol = (tid & 7) * 8;
  const int scol_g = scol ^ (((tid >> 5) & 1) << 4);
  const int NT = K >> 6;

  f32x4 acc[4][3];
#pragma unroll
  for (int i = 0; i < 4; i++)
#pragma unroll
    for (int j = 0; j < 3; j++) acc[i][j] = (f32x4){0.f, 0.f, 0.f, 0.f};

  auto stage = [&](int buf, int kt) {
#pragma unroll
    for (int r = 0; r < 2; r++)
      gload_lds16(A + (size_t)(m0 + r * 64 + srow) * K + kt * 64 + scol_g,
                  &As[((buf * 2 + r) * 64 + srow) * 64 + scol]);
#pragma unroll
    for (int c = 0; c < 3; c++)
      gload_lds16(Bt + (size_t)(n0 + c * 64 + srow) * K + kt * 64 + scol_g,
                  &Bs[((buf * 3 + c) * 64 + srow) * 64 + scol]);
  };

  stage(0, 0);
  asm volatile("s_waitcnt vmcnt(0)" ::: "memory");
  __builtin_amdgcn_s_barrier();

  const int colr = (lg * 8) ^ (((lr >> 2) & 1) << 4);
  const int aB = (wm * 64 + lr) * 64 + colr;
  int bOff[3];
#pragma unroll
  for (int j = 0; j < 3; j++)
    bOff[j] = (wn * 48 + j * 16 + lr) * 64 + colr;

  int cur = 0;
#pragma unroll 1
  for (int t = 0; t < NT; t++) {
    if (t + 1 < NT) stage(cur ^ 1, t + 1);  // issue first; overlaps with compute
    bf16x8 a[4][2], b[3][2];
#pragma unroll
    for (int i = 0; i < 4; i++)
#pragma unroll
      for (int kk = 0; kk < 2; kk++)
        a[i][kk] = *reinterpret_cast<const bf16x8*>(&As[cur * 8192 + i * 1024 + kk * 32 + aB]);
#pragma unroll
    for (int j = 0; j < 3; j++)
#pragma unroll
      for (int kk = 0; kk < 2; kk++)
        b[j][kk] = *reinterpret_cast<const bf16x8*>(&Bs[cur * 12288 + kk * 32 + bOff[j]]);
#pragma unroll
    for (int i = 0; i < 4; i++)
#pragma unroll
      for (int j = 0; j < 3; j++)
#pragma unroll
        for (int kk = 0; kk < 2; kk++)
          acc[i][j] = MFMA16(a[i][kk], b[j][kk], acc[i][j]);
    asm volatile("s_waitcnt vmcnt(0)" ::: "memory");
    __builtin_amdgcn_s_barrier();
    cur ^= 1;
  }

#pragma unroll
  for (int i = 0; i < 4; i++) {
    int row = m0 + wm * 64 + i * 16 + lg * 4;
#pragma unroll
    for (int j = 0; j < 3; j++) {
      int col = n0 + wn * 48 + j * 16 + lr;
      float bsv = bias[col];
#pragma unroll
      for (int r = 0; r < 4; r++)
        C[(size_t)(row + r) * N + col] = f2b(acc[i][j][r] + bsv);
    }
  }
}

// ---------------- 2-phase 128x64 GEMM (output projection) ----------------

template <typename OutT>
__global__ __launch_bounds__(256, 3) void gemm2p_kernel(
    const unsigned short* __restrict__ A, const unsigned short* __restrict__ Bt,
    const float* __restrict__ bias, OutT* __restrict__ C, int N, int K) {
  __shared__ unsigned short As[2 * 128 * 64];
  __shared__ unsigned short Bs[2 * 64 * 64];
  const int tid = threadIdx.x;
  const int cpx = gridDim.x >> 3;
  const int nid = (blockIdx.x & 7) * cpx + (blockIdx.x >> 3);
  const int nbx = N >> 6;
  const int by = nid / nbx, bx = nid - by * nbx;
  const int m0 = by * 128, n0 = bx * 64;
  const int w = tid >> 6, l = tid & 63;
  const int wm = (w >> 1) * 64, wn = (w & 1) * 32;
  const int lr = l & 15, lg = l >> 4;
  const int srow = tid >> 3;
  const int scol = (tid & 7) * 8;
  const int scol_g = scol ^ (((tid >> 5) & 1) << 4);
  const int NT = K >> 6;

  f32x4 acc[4][2];
#pragma unroll
  for (int i = 0; i < 4; i++)
#pragma unroll
    for (int j = 0; j < 2; j++) acc[i][j] = (f32x4){0.f, 0.f, 0.f, 0.f};

  auto stage = [&](int buf, int kt) {
#pragma unroll
    for (int r = 0; r < 4; r++)
      gload_lds16(A + (size_t)(m0 + r * 32 + srow) * K + kt * 64 + scol_g,
                  &As[(buf * 128 + r * 32 + srow) * 64 + scol]);
#pragma unroll
    for (int r = 0; r < 2; r++)
      gload_lds16(Bt + (size_t)(n0 + r * 32 + srow) * K + kt * 64 + scol_g,
                  &Bs[(buf * 64 + r * 32 + srow) * 64 + scol]);
  };

  stage(0, 0);
  asm volatile("s_waitcnt vmcnt(0)" ::: "memory");
  __builtin_amdgcn_s_barrier();

  const int colr = (lg * 8) ^ (((lr >> 2) & 1) << 4);
  const int aB = (wm + lr) * 64 + colr;
  const int bB = (wn + lr) * 64 + colr;

  int cur = 0;
#pragma unroll 1
  for (int t = 0; t < NT; t++) {
    if (t + 1 < NT) stage(cur ^ 1, t + 1);
    bf16x8 a[4][2], b[2][2];
#pragma unroll
    for (int i = 0; i < 4; i++)
#pragma unroll
      for (int kk = 0; kk < 2; kk++)
        a[i][kk] = *reinterpret_cast<const bf16x8*>(&As[cur * 8192 + i * 1024 + kk * 32 + aB]);
#pragma unroll
    for (int j = 0; j < 2; j++)
#pragma unroll
      for (int kk = 0; kk < 2; kk++)
        b[j][kk] = *reinterpret_cast<const bf16x8*>(&Bs[cur * 4096 + j * 1024 + kk * 32 + bB]);
#pragma unroll
    for (int i = 0; i < 4; i++)
#pragma unroll
      for (int j = 0; j < 2; j++)
#pragma unroll
        for (int kk = 0; kk < 2; kk++)
          acc[i][j] = MFMA16(a[i][kk], b[j][kk], acc[i][j]);
    asm volatile("s_waitcnt vmcnt(0)" ::: "memory");
    __builtin_amdgcn_s_barrier();
    cur ^= 1;
  }

#pragma unroll
  for (int i = 0; i < 4; i++) {
    int row = m0 + wm + i * 16 + lg * 4;
#pragma unroll
    for (int j = 0; j < 2; j++) {
      int col = n0 + wn + j * 16 + lr;
      float bsv = bias[col];
#pragma unroll
      for (int r = 0; r < 4; r++)
        storev(&C[(size_t)(row + r) * N + col], acc[i][j][r] + bsv);
    }
  }
}

// ---------------- windowed flash attention (128 q-rows/block) ----------------

__global__ __launch_bounds__(512) void attn_kernel(const unsigned short* __restrict__ qkv,
                                                   unsigned short* __restrict__ attnb) {
  __shared__ unsigned short Ks[64 * 72];
  __shared__ unsigned short Vt[64 * 72];
  __shared__ unsigned short Ps[8][16 * 72];

  const int tid = threadIdx.x;
  const int i0 = blockIdx.x * 128;
  const int h = blockIdx.y;
  const int b = blockIdx.z;
  const int w = tid >> 6, l = tid & 63;
  const int lr = l & 15, lg = l >> 4;
  const size_t rowb = (size_t)b * S_LEN;

  const unsigned short* qptr = qkv + (rowb + i0 + w * 16 + lr) * NQKV + h * HDIM;
  bf16x8 qa[2];
  qa[0] = *reinterpret_cast<const bf16x8*>(qptr + lg * 8);
  qa[1] = *reinterpret_cast<const bf16x8*>(qptr + 32 + lg * 8);

  f32x4 accO[4];
#pragma unroll
  for (int f = 0; f < 4; f++) accO[f] = (f32x4){0.f, 0.f, 0.f, 0.f};
  float Mv[4], Lv[4];
#pragma unroll
  for (int r = 0; r < 4; r++) { Mv[r] = -1e30f; Lv[r] = 0.f; }

  const int wimin = i0 + w * 16;
  const int wimax = wimin + 15;

  for (int c = 0; c < 6; c++) {
    int j0c = i0 - WINSZ + c * 64;
    if (j0c + 63 < 0) continue;  // block-uniform
    __syncthreads();
    {
      int d8 = (tid & 7) * 8;
      int jl = tid >> 3;  // 0..63
      int jg = j0c + jl;
      us8 kv = (us8){0, 0, 0, 0, 0, 0, 0, 0}, vv = (us8){0, 0, 0, 0, 0, 0, 0, 0};
      if (jg >= 0) {
        const unsigned short* kp = qkv + (rowb + jg) * NQKV + DMODEL + h * HDIM + d8;
        kv = *reinterpret_cast<const us8*>(kp);
        vv = *reinterpret_cast<const us8*>(kp + DMODEL);
      }
      *reinterpret_cast<us8*>(&Ks[jl * 72 + d8]) = kv;
      int jsw = jl ^ ((tid & 3) << 3);
#pragma unroll
      for (int e = 0; e < 8; e++) Vt[(d8 + e) * 72 + jsw] = vv[e];
    }
    __syncthreads();

    if (j0c > wimax || j0c + 63 < wimin - WINSZ) continue;  // wave-uniform

    f32x4 sa[4];
#pragma unroll
    for (int f = 0; f < 4; f++) sa[f] = (f32x4){0.f, 0.f, 0.f, 0.f};
#pragma unroll
    for (int f = 0; f < 4; f++) {
      bf16x8 k0v = *reinterpret_cast<const bf16x8*>(&Ks[(f * 16 + lr) * 72 + lg * 8]);
      bf16x8 k1v = *reinterpret_cast<const bf16x8*>(&Ks[(f * 16 + lr) * 72 + 32 + lg * 8]);
      sa[f] = MFMA16(qa[0], k0v, sa[f]);
      sa[f] = MFMA16(qa[1], k1v, sa[f]);
    }
#pragma unroll
    for (int f = 0; f < 4; f++) {
      int jg = j0c + f * 16 + lr;
#pragma unroll
      for (int r = 0; r < 4; r++) {
        int irow = i0 + w * 16 + lg * 4 + r;
        float s = sa[f][r] * 0.125f;
        bool ok = (jg >= 0) && (jg <= irow) && (jg >= irow - WINSZ);
        sa[f][r] = ok ? s : -1e30f;
      }
    }
    float pm[4];
#pragma unroll
    for (int r = 0; r < 4; r++) {
      float m = fmaxf(fmaxf(sa[0][r], sa[1][r]), fmaxf(sa[2][r], sa[3][r]));
#pragma unroll
      for (int off = 1; off < 16; off <<= 1) m = fmaxf(m, __shfl_xor(m, off));
      pm[r] = m;
    }
#pragma unroll
    for (int r = 0; r < 4; r++) {
      float Mn = fmaxf(Mv[r], pm[r]);
      float sc = __expf(Mv[r] - Mn);
      Mv[r] = Mn;
      Lv[r] *= sc;
#pragma unroll
      for (int f = 0; f < 4; f++) accO[f][r] *= sc;
    }
    float rs[4] = {0.f, 0.f, 0.f, 0.f};
#pragma unroll
    for (int f = 0; f < 4; f++) {
#pragma unroll
      for (int r = 0; r < 4; r++) {
        float p = __expf(sa[f][r] - Mv[r]);
        rs[r] += p;
        Ps[w][(lg * 4 + r) * 72 + f * 16 + lr] = f2b(p);
      }
    }
#pragma unroll
    for (int r = 0; r < 4; r++) {
      float s = rs[r];
#pragma unroll
      for (int off = 1; off < 16; off <<= 1) s += __shfl_xor(s, off);
      Lv[r] += s;
    }
    bf16x8 pa0 = *reinterpret_cast<const bf16x8*>(&Ps[w][lr * 72 + lg * 8]);
    bf16x8 pa1 = *reinterpret_cast<const bf16x8*>(&Ps[w][lr * 72 + 32 + lg * 8]);
#pragma unroll
    for (int f = 0; f < 4; f++) {
      int vsw = ((f * 2 + (lr >> 3)) & 3) << 3;
      bf16x8 v0 = *reinterpret_cast<const bf16x8*>(&Vt[(f * 16 + lr) * 72 + ((lg * 8) ^ vsw)]);
      bf16x8 v1 = *reinterpret_cast<const bf16x8*>(&Vt[(f * 16 + lr) * 72 + 32 + ((lg * 8) ^ vsw)]);
      accO[f] = MFMA16(pa0, v0, accO[f]);
      accO[f] = MFMA16(pa1, v1, accO[f]);
    }
  }

#pragma unroll
  for (int f = 0; f < 4; f++) {
#pragma unroll
    for (int r = 0; r < 4; r++) {
      float o = accO[f][r] / Lv[r];
      int row = i0 + w * 16 + lg * 4 + r;
      attnb[(rowb + row) * DMODEL + h * HDIM + f * 16 + lr] = f2b(o);
    }
  }
}

// ---------------- launch ----------------

extern "C" void kernel_launch(void* const* d_in, const int* in_sizes, int n_in,
                              void* d_out, int out_size, void* d_ws, size_t ws_size,
                              hipStream_t stream) {
  const float* x = (const float*)d_in[0];
  const float* Wq = (const float*)d_in[1];
  const float* bq = (const float*)d_in[2];
  const float* Wk = (const float*)d_in[3];
  const float* bk = (const float*)d_in[4];
  const float* Wv = (const float*)d_in[5];
  const float* bv = (const float*)d_in[6];
  const float* Wo = (const float*)d_in[7];
  const float* bo = (const float*)d_in[8];
  float* out = (float*)d_out;

  unsigned short* xb = (unsigned short*)d_ws;                       // 4096*1024
  unsigned short* WqkvT = xb + (size_t)MROWS * DMODEL;              // 3*1024*1024
  unsigned short* WoT = WqkvT + (size_t)3 * DMODEL * DMODEL;        // 1024*1024
  unsigned short* QKV = WoT + (size_t)DMODEL * DMODEL;              // 4096*3072
  unsigned short* attnb = QKV + (size_t)MROWS * NQKV;               // 4096*1024
  float* bqkv = (float*)(attnb + (size_t)MROWS * DMODEL);           // 3072 f32

  prep_kernel<<<8196, 256, 0, stream>>>(x, Wq, Wk, Wv, Wo, bq, bk, bv,
                                        xb, WqkvT, WoT, bqkv);

  gemmqkv_kernel<<<(NQKV / 192) * (MROWS / 128), 512, 0, stream>>>(
      xb, WqkvT, bqkv, QKV, NQKV, DMODEL);

  attn_kernel<<<dim3(S_LEN / 128, NHEAD, 2), 512, 0, stream>>>(QKV, attnb);

  gemm2p_kernel<float><<<(DMODEL / 64) * (MROWS / 128), 256, 0, stream>>>(
      attnb, WoT, bo, out, DMODEL, DMODEL);
}